// Round 4
// baseline (450.750 us; speedup 1.0000x reference)
//
#include <hip/hip_runtime.h>

// SwinV2 window attention, MI355X.
//   prep: cast weights+x -> bf16, CPB table, combined bias comb[h][w][n][52]
//   k_gemm8<false>: qkv = x @ qkv_w^T + b   (256x128x64 tile, 8-wave,
//       2-phase/K-tile counted-vmcnt pipeline, triple-buffered LDS, T2+T5)
//   k_attn: per (window,head); S^T = mfma(K,Q) -> in-register softmax
//   k_gemm8<true>:  out = y @ proj_w^T + b  (f32 out)
// K=384 hardcoded (both GEMMs), KT=6 K-tiles fully unrolled.
//
// Workspace layout (bytes):
//   0          x_bf      77,070,336
//   77070336   qkvw_bf      884,736
//   77955072   projw_bf     294,912
//   78249984   cpb_t        115,248 (pad to 115,712)
//   78365696   qkv_bf   231,211,008
//   309576704  y_bf      77,070,336
//   386647040  comb       7,827,456
//   total ~394.5 MB

typedef float f32x4 __attribute__((ext_vector_type(4)));
typedef __bf16 bf16x8 __attribute__((ext_vector_type(8)));
typedef unsigned short u16;
typedef u16 u16x8 __attribute__((ext_vector_type(8)));
typedef u16 u16x4 __attribute__((ext_vector_type(4)));
typedef unsigned u32x4 __attribute__((ext_vector_type(4)));

__device__ __forceinline__ float b2f(unsigned u) {
  return __builtin_bit_cast(float, u << 16);
}
__device__ __forceinline__ u16 f2b(float f) {  // RNE f32->bf16
  unsigned u = __builtin_bit_cast(unsigned, f);
  u += 0x7fffu + ((u >> 16) & 1u);
  return (u16)(u >> 16);
}
__device__ __forceinline__ unsigned pack2(float a, float b) {
  return (unsigned)f2b(a) | ((unsigned)f2b(b) << 16);
}

#define GLD16(gp, lp)                                        \
  __builtin_amdgcn_global_load_lds(                          \
      (const __attribute__((address_space(1))) void*)(gp),   \
      (__attribute__((address_space(3))) void*)(lp), 16, 0, 0)

// compiler-level fence around the HW barrier: pins LDS/GLD ops in their phase
#define BARF()                            \
  do {                                    \
    asm volatile("" ::: "memory");        \
    __builtin_amdgcn_s_barrier();         \
    asm volatile("" ::: "memory");        \
  } while (0)

// ---------------- cast f32 -> bf16, 8 elems/thread ----------------
__global__ __launch_bounds__(256) void k_cast(const float* __restrict__ in,
                                              u16* __restrict__ out, int n8) {
  int i = blockIdx.x * 256 + threadIdx.x;
  if (i >= n8) return;
  const float4* p = reinterpret_cast<const float4*>(in) + (size_t)i * 2;
  float4 a = p[0], b = p[1];
  u16x8 r;
  r[0] = f2b(a.x); r[1] = f2b(a.y); r[2] = f2b(a.z); r[3] = f2b(a.w);
  r[4] = f2b(b.x); r[5] = f2b(b.y); r[6] = f2b(b.z); r[7] = f2b(b.w);
  *(reinterpret_cast<u16x8*>(out) + i) = r;
}

// ---------------- CPB bias table: cpb_t[h][n][m] ----------------
__global__ __launch_bounds__(64) void k_cpb(const float* __restrict__ w1,
                                            const float* __restrict__ b1,
                                            const float* __restrict__ w2,
                                            const float* __restrict__ b2,
                                            float* __restrict__ cpb_t) {
  int p = blockIdx.x * 64 + threadIdx.x;
  if (p >= 49 * 49) return;
  int n = p / 49, m = p % 49;
  float d0 = (float)(n / 7 - m / 7);
  float d1 = (float)(n % 7 - m % 7);
  float a0 = log1pf(fabsf(d0)); a0 = (d0 < 0.f) ? -a0 : a0;
  float a1 = log1pf(fabsf(d1)); a1 = (d1 < 0.f) ? -a1 : a1;
  float acc[12];
#pragma unroll
  for (int h = 0; h < 12; ++h) acc[h] = b2[h];
  for (int j = 0; j < 64; ++j) {
    float hj = fmaxf(a0 * w1[2 * j] + a1 * w1[2 * j + 1] + b1[j], 0.f);
#pragma unroll
    for (int h = 0; h < 12; ++h) acc[h] += hj * w2[h * 64 + j];
  }
#pragma unroll
  for (int h = 0; h < 12; ++h) cpb_t[h * 2401 + p] = acc[h];
}

// ---------------- combined bias: comb[(h*64+w)*49+n][52] = cpb + mask --------
__global__ __launch_bounds__(256) void k_comb(const float* __restrict__ cpb_t,
                                              const float* __restrict__ mask,
                                              float* __restrict__ comb) {
  const int wh = blockIdx.x;  // h*64 + w
  const int h = wh >> 6, w = wh & 63;
  const float* c = cpb_t + h * 2401;
  const float* m = mask + (size_t)w * 2401;
  float* o = comb + (size_t)wh * 2548;
  for (int p = threadIdx.x; p < 2548; p += 256) {
    int n = p / 52, mc = p % 52;
    float v = (mc < 49) ? c[n * 49 + mc] + m[n * 49 + mc] : 0.f;
    o[p] = v;
  }
}

// ---------------- GEMM: C[M,N] = A[M,K=384] @ W[N,384]^T + bias ----------------
// BM=256 BN=128 BK=64, 512 thr (8 waves 4Mx2N, per-wave 64x64, acc 4x4).
// Triple-buffered LDS (144 KB), K fully unrolled (6 tiles). Per tile: 2 phases
// {8 ds_read_b128 || 3 global_load_lds -> bar -> setprio1 -> 16 MFMA -> setprio0
//  -> bar}; counted vmcnt(6) at tile boundary (drain only at t=4).
// LDS XOR-swizzle both-sides: source col-group g = slot ^ (row&7); ds_read
// applies same XOR -> balanced 8 slots x 8 lanes, no conflicts.
template <bool OUT_F32>
__global__ __launch_bounds__(512, 2) void k_gemm8(
    const u16* __restrict__ A, const u16* __restrict__ W,
    const float* __restrict__ bias, void* __restrict__ Cv, int N) {
  __shared__ __align__(16) u16 sA[3][16384];  // [256][64] per buf
  __shared__ __align__(16) u16 sB[3][8192];   // [128][64] per buf
  const int tid = threadIdx.x;
  // XCD-aware bijective remap (grids divisible by 8)
  const int cpx = (int)(gridDim.x >> 3);
  int bid = (int)blockIdx.x;
  bid = (bid & 7) * cpx + (bid >> 3);
  const int nt = N >> 7;
  const int m0 = (bid / nt) << 8;
  const int n0 = (bid % nt) << 7;

  // staging: issue i covers 64 rows; row = i*64 + (tid>>3), slot = tid&7,
  // global col-group = slot ^ (row&7)  (row&7 == (tid>>3)&7)
  const int r0 = tid >> 3;
  const int g = (((tid & 7) ^ (r0 & 7)) << 3);
  const u16* pAg = A + (size_t)(m0 + r0) * 384 + g;
  const u16* pBg = W + (size_t)(n0 + r0) * 384 + g;

#define GA(buf, t, i) GLD16(pAg + (i) * 24576 + (t) * 64, &sA[buf][(i) * 4096 + tid * 8])
#define GB(buf, t, i) GLD16(pBg + (i) * 24576 + (t) * 64, &sB[buf][(i) * 4096 + tid * 8])

  // prologue: tiles 0 and 1 (6 loads each, FIFO order GA0..3,GB0..1)
  GA(0, 0, 0); GA(0, 0, 1); GA(0, 0, 2); GA(0, 0, 3); GB(0, 0, 0); GB(0, 0, 1);
  GA(1, 1, 0); GA(1, 1, 1); GA(1, 1, 2); GA(1, 1, 3); GB(1, 1, 0); GB(1, 1, 1);

  const int l = tid & 63, w = tid >> 6;
  const int wm = (w & 3) << 6, wn = (w >> 2) << 6;
  const int lr = l & 15, lg = l >> 4;
  const int ax = lr & 7;
  const int sl0 = ((lg ^ ax) << 3), sl1 = (((4 | lg) ^ ax) << 3);
  int aOff[4], bOff[4];
#pragma unroll
  for (int i = 0; i < 4; ++i) {
    aOff[i] = (wm + i * 16 + lr) << 6;
    bOff[i] = (wn + i * 16 + lr) << 6;
  }

  const f32x4 z4 = {0.f, 0.f, 0.f, 0.f};
  f32x4 acc[4][4];
#pragma unroll
  for (int i = 0; i < 4; ++i)
#pragma unroll
    for (int j = 0; j < 4; ++j) acc[i][j] = z4;

  asm volatile("s_waitcnt vmcnt(6)" ::: "memory");  // tile 0 resident
  __builtin_amdgcn_s_barrier();

#pragma unroll
  for (int t = 0; t < 6; ++t) {
    const u16* pa = sA[t % 3];
    const u16* pb = sB[t % 3];
    const int nb = (t + 2) % 3;
    bf16x8 af[4], bq[4];
    // ---- phase 0 (ks=0) ----
#pragma unroll
    for (int mi = 0; mi < 4; ++mi)
      af[mi] = __builtin_bit_cast(bf16x8,
          *reinterpret_cast<const u16x8*>(pa + aOff[mi] + sl0));
#pragma unroll
    for (int ni = 0; ni < 4; ++ni)
      bq[ni] = __builtin_bit_cast(bf16x8,
          *reinterpret_cast<const u16x8*>(pb + bOff[ni] + sl0));
    if (t < 4) { GA(nb, t + 2, 0); GA(nb, t + 2, 1); GA(nb, t + 2, 2); }
    BARF();
    __builtin_amdgcn_s_setprio(1);
#pragma unroll
    for (int mi = 0; mi < 4; ++mi)
#pragma unroll
      for (int ni = 0; ni < 4; ++ni)
        acc[mi][ni] = __builtin_amdgcn_mfma_f32_16x16x32_bf16(
            af[mi], bq[ni], acc[mi][ni], 0, 0, 0);
    __builtin_amdgcn_s_setprio(0);
    BARF();
    // ---- phase 1 (ks=1) ----
#pragma unroll
    for (int mi = 0; mi < 4; ++mi)
      af[mi] = __builtin_bit_cast(bf16x8,
          *reinterpret_cast<const u16x8*>(pa + aOff[mi] + sl1));
#pragma unroll
    for (int ni = 0; ni < 4; ++ni)
      bq[ni] = __builtin_bit_cast(bf16x8,
          *reinterpret_cast<const u16x8*>(pb + bOff[ni] + sl1));
    if (t < 4) { GA(nb, t + 2, 3); GB(nb, t + 2, 0); GB(nb, t + 2, 1); }
    BARF();
    __builtin_amdgcn_s_setprio(1);
#pragma unroll
    for (int mi = 0; mi < 4; ++mi)
#pragma unroll
      for (int ni = 0; ni < 4; ++ni)
        acc[mi][ni] = __builtin_amdgcn_mfma_f32_16x16x32_bf16(
            af[mi], bq[ni], acc[mi][ni], 0, 0, 0);
    __builtin_amdgcn_s_setprio(0);
    // tile boundary: need tile t+1 resident; keep tile t+2's 6 loads in flight
    if (t < 4) {
      asm volatile("s_waitcnt vmcnt(6)" ::: "memory");
    } else if (t == 4) {
      asm volatile("s_waitcnt vmcnt(0)" ::: "memory");
    }
    BARF();
  }
#undef GA
#undef GB

  float bv[4];
#pragma unroll
  for (int ni = 0; ni < 4; ++ni) bv[ni] = bias[n0 + wn + ni * 16 + lr];
#pragma unroll
  for (int mi = 0; mi < 4; ++mi)
#pragma unroll
    for (int rr = 0; rr < 4; ++rr) {
      const size_t row = (size_t)(m0 + wm + mi * 16 + lg * 4 + rr);
#pragma unroll
      for (int ni = 0; ni < 4; ++ni) {
        const int col = n0 + wn + ni * 16 + lr;
        float v = acc[mi][ni][rr] + bv[ni];
        if (OUT_F32)
          reinterpret_cast<float*>(Cv)[row * N + col] = v;
        else
          reinterpret_cast<u16*>(Cv)[row * N + col] = f2b(v);
      }
    }
}

// ---------------- attention: one wave per (window b, head h) ----------------
__global__ __launch_bounds__(64, 4) void k_attn(
    const u16* __restrict__ qkv, const float* __restrict__ tau,
    const float* __restrict__ comb, u16* __restrict__ y) {
  const int b = blockIdx.x, h = blockIdx.y;
  const int l = threadIdx.x;
  __shared__ __align__(16) u16 lk[64][40];  // 5120 B, overlaid by vt
  __shared__ __align__(16) u16 lq[64][40];  // 5120 B, live throughout
  u16(*vt)[72] = reinterpret_cast<u16(*)[72]>(&lk[0][0]);  // [32][72]

  const float tauh = fmaxf(tau[h], 0.01f);
  const bool valid = l < 49;
  u16x8 v8s[4];
  {
    const u16* base = qkv + ((size_t)b * 49 + (valid ? l : 0)) * 1152 + h * 32;
    float qv[32], kv[32];
#pragma unroll
    for (int c = 0; c < 4; ++c) {
      u16x8 q8 = {0, 0, 0, 0, 0, 0, 0, 0};
      u16x8 k8 = {0, 0, 0, 0, 0, 0, 0, 0};
      u16x8 v8 = {0, 0, 0, 0, 0, 0, 0, 0};
      if (valid) {
        q8 = *reinterpret_cast<const u16x8*>(base + c * 8);
        k8 = *reinterpret_cast<const u16x8*>(base + 384 + c * 8);
        v8 = *reinterpret_cast<const u16x8*>(base + 768 + c * 8);
      }
      v8s[c] = v8;
#pragma unroll
      for (int e = 0; e < 8; ++e) {
        qv[c * 8 + e] = b2f((unsigned)q8[e]);
        kv[c * 8 + e] = b2f((unsigned)k8[e]);
      }
    }
    float sq = 0.f, sk = 0.f;
#pragma unroll
    for (int j = 0; j < 32; ++j) { sq += qv[j] * qv[j]; sk += kv[j] * kv[j]; }
    const float qs = (1.f / fmaxf(sqrtf(sq), 1e-12f)) / tauh;  // fold 1/tau
    const float ks = 1.f / fmaxf(sqrtf(sk), 1e-12f);
#pragma unroll
    for (int c = 0; c < 4; ++c) {
      u16x8 wq, wk;
#pragma unroll
      for (int e = 0; e < 8; ++e) {
        wq[e] = f2b(qv[c * 8 + e] * qs);
        wk[e] = f2b(kv[c * 8 + e] * ks);
      }
      *reinterpret_cast<u16x8*>(&lq[l][c * 8]) = wq;
      *reinterpret_cast<u16x8*>(&lk[l][c * 8]) = wk;
    }
  }
  __syncthreads();

  const int lr = l & 15, lg = l >> 4;
  bf16x8 kf[4];
#pragma unroll
  for (int mi = 0; mi < 4; ++mi)
    kf[mi] = __builtin_bit_cast(bf16x8,
        *reinterpret_cast<const u16x8*>(&lk[mi * 16 + lr][lg * 8]));
  __syncthreads();  // lk dead -> overlay vt
#pragma unroll
  for (int c = 0; c < 4; ++c)
#pragma unroll
    for (int e = 0; e < 8; ++e) vt[c * 8 + e][l] = v8s[c][e];
  __syncthreads();
  bf16x8 vtf[2][2];
#pragma unroll
  for (int dd = 0; dd < 2; ++dd)
#pragma unroll
    for (int ks = 0; ks < 2; ++ks)
      vtf[dd][ks] = __builtin_bit_cast(bf16x8,
          *reinterpret_cast<const u16x8*>(&vt[dd * 16 + lr][ks * 32 + lg * 8]));

  const f32x4 z4 = {0.f, 0.f, 0.f, 0.f};
  const int src0 = lr + 16 * ((2 * lg) & 3);
  const int src1 = lr + 16 * ((2 * lg + 1) & 3);
  const bool hi5 = lg >= 2;
  const float* bbase = comb + (size_t)(h * 64 + (b & 63)) * 2548;

#pragma unroll
  for (int nj = 0; nj < 4; ++nj) {
    const bf16x8 qf = __builtin_bit_cast(bf16x8,
        *reinterpret_cast<const u16x8*>(&lq[nj * 16 + lr][lg * 8]));
    f32x4 s[4];
#pragma unroll
    for (int mi = 0; mi < 4; ++mi)
      s[mi] = __builtin_amdgcn_mfma_f32_16x16x32_bf16(kf[mi], qf, z4, 0, 0, 0);

    const int n = nj * 16 + lr;
    const float* bp = bbase + (size_t)(n < 49 ? n : 48) * 52 + lg * 4;
    f32x4 bia[4];
#pragma unroll
    for (int mi = 0; mi < 4; ++mi)
      bia[mi] = *reinterpret_cast<const f32x4*>(bp + mi * 16);

    float v[4][4];
#pragma unroll
    for (int mi = 0; mi < 3; ++mi)  // m <= 47: all valid
#pragma unroll
      for (int r = 0; r < 4; ++r) v[mi][r] = s[mi][r] + bia[mi][r];
#pragma unroll
    for (int r = 0; r < 4; ++r) {  // mi=3: only m=48 (lg==0, r==0) valid
      float t = s[3][r] + bia[3][r];
      v[3][r] = (lg == 0 && r == 0) ? t : -1e30f;
    }

    float mx = v[0][0];
#pragma unroll
    for (int mi = 0; mi < 4; ++mi)
#pragma unroll
      for (int r = 0; r < 4; ++r) mx = fmaxf(mx, v[mi][r]);
    mx = fmaxf(mx, __shfl_xor(mx, 16));
    mx = fmaxf(mx, __shfl_xor(mx, 32));
    float sum = 0.f;
#pragma unroll
    for (int mi = 0; mi < 4; ++mi)
#pragma unroll
      for (int r = 0; r < 4; ++r) {
        v[mi][r] = __expf(v[mi][r] - mx);
        sum += v[mi][r];
      }
    sum += __shfl_xor(sum, 16);
    sum += __shfl_xor(sum, 32);
    const float rinv = __builtin_amdgcn_rcpf(sum);

    unsigned pk[4][2];
#pragma unroll
    for (int mi = 0; mi < 4; ++mi) {
      pk[mi][0] = pack2(v[mi][0] * rinv, v[mi][1] * rinv);
      pk[mi][1] = pack2(v[mi][2] * rinv, v[mi][3] * rinv);
    }
    // redistribute: pf[ks] elem e = P^T[ks*32+lg*8+e][n]
    bf16x8 pf[2];
#pragma unroll
    for (int ks = 0; ks < 2; ++ks) {
      unsigned a0 = (unsigned)__shfl((int)pk[2 * ks][0], src0);
      unsigned b0 = (unsigned)__shfl((int)pk[2 * ks + 1][0], src0);
      unsigned a1 = (unsigned)__shfl((int)pk[2 * ks][1], src0);
      unsigned b1 = (unsigned)__shfl((int)pk[2 * ks + 1][1], src0);
      unsigned a2 = (unsigned)__shfl((int)pk[2 * ks][0], src1);
      unsigned b2_ = (unsigned)__shfl((int)pk[2 * ks + 1][0], src1);
      unsigned a3 = (unsigned)__shfl((int)pk[2 * ks][1], src1);
      unsigned b3 = (unsigned)__shfl((int)pk[2 * ks + 1][1], src1);
      u32x4 ww = {hi5 ? b0 : a0, hi5 ? b1 : a1, hi5 ? b2_ : a2, hi5 ? b3 : a3};
      pf[ks] = __builtin_bit_cast(bf16x8, ww);
    }

    f32x4 o0 = __builtin_amdgcn_mfma_f32_16x16x32_bf16(vtf[0][0], pf[0], z4, 0, 0, 0);
    o0 = __builtin_amdgcn_mfma_f32_16x16x32_bf16(vtf[0][1], pf[1], o0, 0, 0, 0);
    f32x4 o1 = __builtin_amdgcn_mfma_f32_16x16x32_bf16(vtf[1][0], pf[0], z4, 0, 0, 0);
    o1 = __builtin_amdgcn_mfma_f32_16x16x32_bf16(vtf[1][1], pf[1], o1, 0, 0, 0);

    if (n < 49) {
      u16* dst = y + ((size_t)b * 49 + n) * 384 + h * 32 + lg * 4;
      u16x4 w0 = {f2b(o0[0]), f2b(o0[1]), f2b(o0[2]), f2b(o0[3])};
      u16x4 w1 = {f2b(o1[0]), f2b(o1[1]), f2b(o1[2]), f2b(o1[3])};
      *reinterpret_cast<u16x4*>(dst) = w0;
      *reinterpret_cast<u16x4*>(dst + 16) = w1;
    }
  }
}

// ---------------- launcher ----------------
extern "C" void kernel_launch(void* const* d_in, const int* in_sizes, int n_in,
                              void* d_out, int out_size, void* d_ws,
                              size_t ws_size, hipStream_t stream) {
  (void)in_sizes; (void)n_in; (void)out_size; (void)ws_size;
  const float* x      = (const float*)d_in[0];
  const float* mask   = (const float*)d_in[1];
  const float* qkv_w  = (const float*)d_in[2];
  const float* qkv_b  = (const float*)d_in[3];
  const float* tau    = (const float*)d_in[4];
  const float* cpb_w1 = (const float*)d_in[5];
  const float* cpb_b1 = (const float*)d_in[6];
  const float* cpb_w2 = (const float*)d_in[7];
  const float* cpb_b2 = (const float*)d_in[8];
  const float* proj_w = (const float*)d_in[9];
  const float* proj_b = (const float*)d_in[10];
  float* out = (float*)d_out;

  char* ws = (char*)d_ws;
  u16* x_bf     = (u16*)(ws);
  u16* qkvw_bf  = (u16*)(ws + 77070336);
  u16* projw_bf = (u16*)(ws + 77955072);
  float* cpb_t  = (float*)(ws + 78249984);
  u16* qkv_bf   = (u16*)(ws + 78365696);
  u16* y_bf     = (u16*)(ws + 309576704);
  float* comb   = (float*)(ws + 386647040);

  k_cast<<<dim3(18816), dim3(256), 0, stream>>>(x, x_bf, 4816896);
  k_cast<<<dim3(216), dim3(256), 0, stream>>>(qkv_w, qkvw_bf, 55296);
  k_cast<<<dim3(72), dim3(256), 0, stream>>>(proj_w, projw_bf, 18432);
  k_cpb<<<dim3(38), dim3(64), 0, stream>>>(cpb_w1, cpb_b1, cpb_w2, cpb_b2, cpb_t);
  k_comb<<<dim3(768), dim3(256), 0, stream>>>(cpb_t, mask, comb);

  // qkv = x @ qkv_w^T + qkv_b   (M=100352, N=1152, K=384): 392 x 9 tiles
  k_gemm8<false><<<dim3(392 * 9), dim3(512), 0, stream>>>(
      x_bf, qkvw_bf, qkv_b, qkv_bf, 1152);

  k_attn<<<dim3(2048, 12), dim3(64), 0, stream>>>(qkv_bf, tau, comb, y_bf);

  // out = y @ proj_w^T + proj_b (M=100352, N=384, K=384): 392 x 3 tiles
  k_gemm8<true><<<dim3(392 * 3), dim3(512), 0, stream>>>(
      y_bf, projw_bf, proj_b, out, 384);
}

// Round 5
// 443.764 us; speedup vs baseline: 1.0157x; 1.0157x over previous
//
#include <hip/hip_runtime.h>

// SwinV2 window attention, MI355X.
//   prep: cast weights+x -> bf16, CPB table, combined bias comb[h][w][n][52]
//   k_gemmQ: qkv = x @ qkv_w^T + b, N padded 1152->1280 (=5x256).
//       m201-style: BM=BN=256, BK=32, 8 waves (2Mx4N, per-wave 128x64),
//       4-buffer LDS (128KB), counted vmcnt(8), 2 phases/K-tile, T2+T5.
//   k_attn: per (window,head); S^T = mfma(K,Q) -> in-register softmax
//   k_gemm_bt<true>: out = y @ proj_w^T + b (proven R3 2-phase 128^2)
//
// Workspace layout (bytes):
//   0          x_bf      77,070,336   (overlaid by y_bf after qkv GEMM)
//   77070336   qkvw_bf      983,040   ([1280][384], rows 1152+ zeroed)
//   78053376   projw_bf     294,912
//   78348288   cpb_t        115,712
//   78464000   qkvb_pad       5,120   (f32[1280], tail zeroed)
//   78469120   qkv_bf   256,901,120   ([100352][1280] bf16)
//   335370240  comb       7,827,456
//   total ~343 MB

typedef float f32x4 __attribute__((ext_vector_type(4)));
typedef __bf16 bf16x8 __attribute__((ext_vector_type(8)));
typedef unsigned short u16;
typedef u16 u16x8 __attribute__((ext_vector_type(8)));
typedef u16 u16x4 __attribute__((ext_vector_type(4)));
typedef unsigned u32x4 __attribute__((ext_vector_type(4)));

__device__ __forceinline__ float b2f(unsigned u) {
  return __builtin_bit_cast(float, u << 16);
}
__device__ __forceinline__ u16 f2b(float f) {  // RNE f32->bf16
  unsigned u = __builtin_bit_cast(unsigned, f);
  u += 0x7fffu + ((u >> 16) & 1u);
  return (u16)(u >> 16);
}
__device__ __forceinline__ unsigned pack2(float a, float b) {
  return (unsigned)f2b(a) | ((unsigned)f2b(b) << 16);
}

#define GLD16(gp, lp)                                        \
  __builtin_amdgcn_global_load_lds(                          \
      (const __attribute__((address_space(1))) void*)(gp),   \
      (__attribute__((address_space(3))) void*)(lp), 16, 0, 0)

#define BARF()                            \
  do {                                    \
    asm volatile("" ::: "memory");        \
    __builtin_amdgcn_s_barrier();         \
    asm volatile("" ::: "memory");        \
  } while (0)

// ---------------- cast f32 -> bf16, 8 elems/thread ----------------
__global__ __launch_bounds__(256) void k_cast(const float* __restrict__ in,
                                              u16* __restrict__ out, int n8) {
  int i = blockIdx.x * 256 + threadIdx.x;
  if (i >= n8) return;
  const float4* p = reinterpret_cast<const float4*>(in) + (size_t)i * 2;
  float4 a = p[0], b = p[1];
  u16x8 r;
  r[0] = f2b(a.x); r[1] = f2b(a.y); r[2] = f2b(a.z); r[3] = f2b(a.w);
  r[4] = f2b(b.x); r[5] = f2b(b.y); r[6] = f2b(b.z); r[7] = f2b(b.w);
  *(reinterpret_cast<u16x8*>(out) + i) = r;
}

// ---------------- CPB bias table: cpb_t[h][n][m] ----------------
__global__ __launch_bounds__(64) void k_cpb(const float* __restrict__ w1,
                                            const float* __restrict__ b1,
                                            const float* __restrict__ w2,
                                            const float* __restrict__ b2,
                                            float* __restrict__ cpb_t) {
  int p = blockIdx.x * 64 + threadIdx.x;
  if (p >= 49 * 49) return;
  int n = p / 49, m = p % 49;
  float d0 = (float)(n / 7 - m / 7);
  float d1 = (float)(n % 7 - m % 7);
  float a0 = log1pf(fabsf(d0)); a0 = (d0 < 0.f) ? -a0 : a0;
  float a1 = log1pf(fabsf(d1)); a1 = (d1 < 0.f) ? -a1 : a1;
  float acc[12];
#pragma unroll
  for (int h = 0; h < 12; ++h) acc[h] = b2[h];
  for (int j = 0; j < 64; ++j) {
    float hj = fmaxf(a0 * w1[2 * j] + a1 * w1[2 * j + 1] + b1[j], 0.f);
#pragma unroll
    for (int h = 0; h < 12; ++h) acc[h] += hj * w2[h * 64 + j];
  }
#pragma unroll
  for (int h = 0; h < 12; ++h) cpb_t[h * 2401 + p] = acc[h];
}

// ---------------- combined bias: comb[(h*64+w)*49+n][52] = cpb + mask --------
__global__ __launch_bounds__(256) void k_comb(const float* __restrict__ cpb_t,
                                              const float* __restrict__ mask,
                                              float* __restrict__ comb) {
  const int wh = blockIdx.x;  // h*64 + w
  const int h = wh >> 6, w = wh & 63;
  const float* c = cpb_t + h * 2401;
  const float* m = mask + (size_t)w * 2401;
  float* o = comb + (size_t)wh * 2548;
  for (int p = threadIdx.x; p < 2548; p += 256) {
    int n = p / 52, mc = p % 52;
    float v = (mc < 49) ? c[n * 49 + mc] + m[n * 49 + mc] : 0.f;
    o[p] = v;
  }
}

// ---------------- qkv GEMM: C[100352,1280] = A[100352,384] @ W[1280,384]^T --
// BM=BN=256, BK=32, 512 thr, 8 waves 2Mx4N, per-wave 128x64 (acc 8x4).
// 4-buf LDS (32KB/tile, 128KB), prefetch distance 3, counted vmcnt(8).
// Per tile: 2 phases {8 ds_read_b128 || 2 gld_lds -> bar -> prio1 -> 16 MFMA
// -> prio0 -> bar}. XOR swizzle both sides: slot ^= (row>>1)&3 (R3-proven 0cf).
__global__ __launch_bounds__(512, 2) void k_gemmQ(
    const u16* __restrict__ A, const u16* __restrict__ W,
    const float* __restrict__ bias, u16* __restrict__ C) {
  __shared__ __align__(16) u16 sA[4][8192];  // [256][32] per buf
  __shared__ __align__(16) u16 sB[4][8192];
  const int tid = threadIdx.x;
  const int cpx = (int)(gridDim.x >> 3);
  int bid = (int)blockIdx.x;
  bid = (bid & 7) * cpx + (bid >> 3);
  const int m0 = (bid / 5) << 8;
  const int n0 = (bid % 5) << 8;

  // staging: thread covers 16B; issue i adds 128 rows. row r0 = tid>>2,
  // slot tid&3 holds global col-group (tid&3)^((r0>>1)&3).
  const int r0 = tid >> 2;
  const int gc = (((tid & 3) ^ ((r0 >> 1) & 3)) << 3);
  const u16* pA = A + (size_t)(m0 + r0) * 384 + gc;
  const u16* pB = W + (size_t)(n0 + r0) * 384 + gc;

#define QA(buf, t, i) GLD16(pA + (size_t)(i)*49152 + (t)*32, &sA[buf][(i)*4096 + tid * 8])
#define QB(buf, t, i) GLD16(pB + (size_t)(i)*49152 + (t)*32, &sB[buf][(i)*4096 + tid * 8])

  // prologue: tiles 0..2 (4 loads each: A0,A1,B0,B1)
  QA(0, 0, 0); QA(0, 0, 1); QB(0, 0, 0); QB(0, 0, 1);
  QA(1, 1, 0); QA(1, 1, 1); QB(1, 1, 0); QB(1, 1, 1);
  QA(2, 2, 0); QA(2, 2, 1); QB(2, 2, 0); QB(2, 2, 1);

  const int l = tid & 63, w = tid >> 6;
  const int wr = w >> 2, wc = w & 3;
  const int lr = l & 15, lg = l >> 4;
  const int sl = ((lg ^ ((lr >> 1) & 3)) << 3);
  int aOff[8], bOff[4];
#pragma unroll
  for (int i = 0; i < 8; ++i) aOff[i] = ((wr * 128 + i * 16 + lr) << 5) + sl;
#pragma unroll
  for (int i = 0; i < 4; ++i) bOff[i] = ((wc * 64 + i * 16 + lr) << 5) + sl;

  const f32x4 z4 = {0.f, 0.f, 0.f, 0.f};
  f32x4 acc[8][4];
#pragma unroll
  for (int i = 0; i < 8; ++i)
#pragma unroll
    for (int j = 0; j < 4; ++j) acc[i][j] = z4;

  asm volatile("s_waitcnt vmcnt(8)" ::: "memory");  // tile 0 resident
  __builtin_amdgcn_s_barrier();

#pragma unroll
  for (int t = 0; t < 12; ++t) {
    const u16* pa = sA[t & 3];
    const u16* pb = sB[t & 3];
    const int nb = (t + 3) & 3;
    bf16x8 af[4], bq[4];
    // ---- phase 0: A-frags 0-3 x B-frags 0-3 ----
#pragma unroll
    for (int i = 0; i < 4; ++i)
      af[i] = __builtin_bit_cast(bf16x8,
          *reinterpret_cast<const u16x8*>(pa + aOff[i]));
#pragma unroll
    for (int i = 0; i < 4; ++i)
      bq[i] = __builtin_bit_cast(bf16x8,
          *reinterpret_cast<const u16x8*>(pb + bOff[i]));
    if (t < 9) { QA(nb, t + 3, 0); QA(nb, t + 3, 1); }
    BARF();
    __builtin_amdgcn_s_setprio(1);
#pragma unroll
    for (int fa = 0; fa < 4; ++fa)
#pragma unroll
      for (int fb = 0; fb < 4; ++fb)
        acc[fa][fb] = __builtin_amdgcn_mfma_f32_16x16x32_bf16(
            af[fa], bq[fb], acc[fa][fb], 0, 0, 0);
    __builtin_amdgcn_s_setprio(0);
    BARF();
    // ---- phase 1: A-frags 4-7 x B-frags 0-3 (B re-read) ----
#pragma unroll
    for (int i = 0; i < 4; ++i)
      af[i] = __builtin_bit_cast(bf16x8,
          *reinterpret_cast<const u16x8*>(pa + aOff[4 + i]));
#pragma unroll
    for (int i = 0; i < 4; ++i)
      bq[i] = __builtin_bit_cast(bf16x8,
          *reinterpret_cast<const u16x8*>(pb + bOff[i]));
    if (t < 9) { QB(nb, t + 3, 0); QB(nb, t + 3, 1); }
    BARF();
    __builtin_amdgcn_s_setprio(1);
#pragma unroll
    for (int fa = 0; fa < 4; ++fa)
#pragma unroll
      for (int fb = 0; fb < 4; ++fb)
        acc[4 + fa][fb] = __builtin_amdgcn_mfma_f32_16x16x32_bf16(
            af[fa], bq[fb], acc[4 + fa][fb], 0, 0, 0);
    __builtin_amdgcn_s_setprio(0);
    // tile boundary: need T(t+1) resident; keep {T(t+2),T(t+3)} in flight
    if (t <= 8) {
      asm volatile("s_waitcnt vmcnt(8)" ::: "memory");
    } else if (t == 9) {
      asm volatile("s_waitcnt vmcnt(4)" ::: "memory");
    } else if (t == 10) {
      asm volatile("s_waitcnt vmcnt(0)" ::: "memory");
    }
    BARF();
  }
#undef QA
#undef QB

  float bv[4];
#pragma unroll
  for (int fb = 0; fb < 4; ++fb) bv[fb] = bias[n0 + wc * 64 + fb * 16 + lr];
#pragma unroll
  for (int fa = 0; fa < 8; ++fa)
#pragma unroll
    for (int rr = 0; rr < 4; ++rr) {
      const size_t row = (size_t)(m0 + wr * 128 + fa * 16 + lg * 4 + rr);
#pragma unroll
      for (int fb = 0; fb < 4; ++fb) {
        const int col = n0 + wc * 64 + fb * 16 + lr;
        C[row * 1280 + col] = f2b(acc[fa][fb][rr] + bv[fb]);
      }
    }
}

// ---------------- proj GEMM (R3-proven): C[M,N] = A[M,K] @ W[N,K]^T + bias --
template <bool OUT_F32>
__global__ __launch_bounds__(256) void k_gemm_bt(
    const u16* __restrict__ A, const u16* __restrict__ W,
    const float* __restrict__ bias, void* __restrict__ Cv,
    int M, int N, int K) {
  (void)M;
  __shared__ __align__(16) u16 sA[2][4096];  // [128][32]
  __shared__ __align__(16) u16 sB[2][4096];
  const int tid = threadIdx.x;
  const int cpx = (int)(gridDim.x >> 3);
  int bid = (int)blockIdx.x;
  bid = (bid & 7) * cpx + (bid >> 3);
  const int nt = N >> 7;
  const int m0 = (bid / nt) << 7;
  const int n0 = (bid % nt) << 7;
  const int srow = tid >> 2;
  const int scs = (((tid & 3) ^ ((srow >> 1) & 3)) << 3);
  const u16* ga0 = A + (size_t)(m0 + srow) * K + scs;
  const u16* ga1 = ga0 + (size_t)64 * K;
  const u16* gw0 = W + (size_t)(n0 + srow) * K + scs;
  const u16* gw1 = gw0 + (size_t)64 * K;
  const int KT = K >> 5;

#define STAGE(buf, kk)                              \
  do {                                              \
    GLD16(ga0 + (kk), &sA[buf][tid * 8]);           \
    GLD16(ga1 + (kk), &sA[buf][2048 + tid * 8]);    \
    GLD16(gw0 + (kk), &sB[buf][tid * 8]);           \
    GLD16(gw1 + (kk), &sB[buf][2048 + tid * 8]);    \
  } while (0)

  STAGE(0, 0);

  const f32x4 z4 = {0.f, 0.f, 0.f, 0.f};
  f32x4 acc[4][4];
#pragma unroll
  for (int i = 0; i < 4; ++i)
#pragma unroll
    for (int j = 0; j < 4; ++j) acc[i][j] = z4;

  const int l = tid & 63, w = tid >> 6;
  const int wm = (w >> 1) << 6, wn = (w & 1) << 6;
  const int lr = l & 15, lg = l >> 4;
  const int arow = wm + lr, brow = wn + lr;
  const int cg = ((lg ^ ((lr >> 1) & 3)) << 3);

  for (int t = 0; t < KT; ++t) {
    __syncthreads();
    if (t + 1 < KT) STAGE((t + 1) & 1, (t + 1) * 32);
    const u16* pa = sA[t & 1];
    const u16* pb = sB[t & 1];
    bf16x8 af[4], bfv[4];
#pragma unroll
    for (int mi = 0; mi < 4; ++mi)
      af[mi] = __builtin_bit_cast(bf16x8,
          *reinterpret_cast<const u16x8*>(pa + (arow + mi * 16) * 32 + cg));
#pragma unroll
    for (int ni = 0; ni < 4; ++ni)
      bfv[ni] = __builtin_bit_cast(bf16x8,
          *reinterpret_cast<const u16x8*>(pb + (brow + ni * 16) * 32 + cg));
#pragma unroll
    for (int mi = 0; mi < 4; ++mi)
#pragma unroll
      for (int ni = 0; ni < 4; ++ni)
        acc[mi][ni] = __builtin_amdgcn_mfma_f32_16x16x32_bf16(
            af[mi], bfv[ni], acc[mi][ni], 0, 0, 0);
  }
#undef STAGE

  float bv[4];
#pragma unroll
  for (int ni = 0; ni < 4; ++ni) bv[ni] = bias[n0 + wn + ni * 16 + lr];
#pragma unroll
  for (int mi = 0; mi < 4; ++mi)
#pragma unroll
    for (int r = 0; r < 4; ++r) {
      const size_t row = (size_t)(m0 + wm + mi * 16 + lg * 4 + r);
#pragma unroll
      for (int ni = 0; ni < 4; ++ni) {
        const int col = n0 + wn + ni * 16 + lr;
        float v = acc[mi][ni][r] + bv[ni];
        if (OUT_F32)
          reinterpret_cast<float*>(Cv)[row * N + col] = v;
        else
          reinterpret_cast<u16*>(Cv)[row * N + col] = f2b(v);
      }
    }
}

// ---------------- attention: one wave per (window b, head h) ----------------
__global__ __launch_bounds__(64, 4) void k_attn(
    const u16* __restrict__ qkv, const float* __restrict__ tau,
    const float* __restrict__ comb, u16* __restrict__ y) {
  const int b = blockIdx.x, h = blockIdx.y;
  const int l = threadIdx.x;
  __shared__ __align__(16) u16 lk[64][40];  // 5120 B, overlaid by vt
  __shared__ __align__(16) u16 lq[64][40];  // 5120 B, live throughout
  u16(*vt)[72] = reinterpret_cast<u16(*)[72]>(&lk[0][0]);  // [32][72]

  const float tauh = fmaxf(tau[h], 0.01f);
  const bool valid = l < 49;
  u16x8 v8s[4];
  {
    const u16* base = qkv + ((size_t)b * 49 + (valid ? l : 0)) * 1280 + h * 32;
    float qv[32], kv[32];
#pragma unroll
    for (int c = 0; c < 4; ++c) {
      u16x8 q8 = {0, 0, 0, 0, 0, 0, 0, 0};
      u16x8 k8 = {0, 0, 0, 0, 0, 0, 0, 0};
      u16x8 v8 = {0, 0, 0, 0, 0, 0, 0, 0};
      if (valid) {
        q8 = *reinterpret_cast<const u16x8*>(base + c * 8);
        k8 = *reinterpret_cast<const u16x8*>(base + 384 + c * 8);
        v8 = *reinterpret_cast<const u16x8*>(base + 768 + c * 8);
      }
      v8s[c] = v8;
#pragma unroll
      for (int e = 0; e < 8; ++e) {
        qv[c * 8 + e] = b2f((unsigned)q8[e]);
        kv[c * 8 + e] = b2f((unsigned)k8[e]);
      }
    }
    float sq = 0.f, sk = 0.f;
#pragma unroll
    for (int j = 0; j < 32; ++j) { sq += qv[j] * qv[j]; sk += kv[j] * kv[j]; }
    const float qs = (1.f / fmaxf(sqrtf(sq), 1e-12f)) / tauh;  // fold 1/tau
    const float ks = 1.f / fmaxf(sqrtf(sk), 1e-12f);
#pragma unroll
    for (int c = 0; c < 4; ++c) {
      u16x8 wq, wk;
#pragma unroll
      for (int e = 0; e < 8; ++e) {
        wq[e] = f2b(qv[c * 8 + e] * qs);
        wk[e] = f2b(kv[c * 8 + e] * ks);
      }
      *reinterpret_cast<u16x8*>(&lq[l][c * 8]) = wq;
      *reinterpret_cast<u16x8*>(&lk[l][c * 8]) = wk;
    }
  }
  __syncthreads();

  const int lr = l & 15, lg = l >> 4;
  bf16x8 kf[4];
#pragma unroll
  for (int mi = 0; mi < 4; ++mi)
    kf[mi] = __builtin_bit_cast(bf16x8,
        *reinterpret_cast<const u16x8*>(&lk[mi * 16 + lr][lg * 8]));
  __syncthreads();  // lk dead -> overlay vt
#pragma unroll
  for (int c = 0; c < 4; ++c)
#pragma unroll
    for (int e = 0; e < 8; ++e) vt[c * 8 + e][l] = v8s[c][e];
  __syncthreads();
  bf16x8 vtf[2][2];
#pragma unroll
  for (int dd = 0; dd < 2; ++dd)
#pragma unroll
    for (int ks = 0; ks < 2; ++ks)
      vtf[dd][ks] = __builtin_bit_cast(bf16x8,
          *reinterpret_cast<const u16x8*>(&vt[dd * 16 + lr][ks * 32 + lg * 8]));

  const f32x4 z4 = {0.f, 0.f, 0.f, 0.f};
  const int src0 = lr + 16 * ((2 * lg) & 3);
  const int src1 = lr + 16 * ((2 * lg + 1) & 3);
  const bool hi5 = lg >= 2;
  const float* bbase = comb + (size_t)(h * 64 + (b & 63)) * 2548;

#pragma unroll
  for (int nj = 0; nj < 4; ++nj) {
    const bf16x8 qf = __builtin_bit_cast(bf16x8,
        *reinterpret_cast<const u16x8*>(&lq[nj * 16 + lr][lg * 8]));
    f32x4 s[4];
#pragma unroll
    for (int mi = 0; mi < 4; ++mi)
      s[mi] = __builtin_amdgcn_mfma_f32_16x16x32_bf16(kf[mi], qf, z4, 0, 0, 0);

    const int n = nj * 16 + lr;
    const float* bp = bbase + (size_t)(n < 49 ? n : 48) * 52 + lg * 4;
    f32x4 bia[4];
#pragma unroll
    for (int mi = 0; mi < 4; ++mi)
      bia[mi] = *reinterpret_cast<const f32x4*>(bp + mi * 16);

    float v[4][4];
#pragma unroll
    for (int mi = 0; mi < 3; ++mi)  // m <= 47: all valid
#pragma unroll
      for (int r = 0; r < 4; ++r) v[mi][r] = s[mi][r] + bia[mi][r];
#pragma unroll
    for (int r = 0; r < 4; ++r) {  // mi=3: only m=48 (lg==0, r==0) valid
      float t = s[3][r] + bia[3][r];
      v[3][r] = (lg == 0 && r == 0) ? t : -1e30f;
    }

    float mx = v[0][0];
#pragma unroll
    for (int mi = 0; mi < 4; ++mi)
#pragma unroll
      for (int r = 0; r < 4; ++r) mx = fmaxf(mx, v[mi][r]);
    mx = fmaxf(mx, __shfl_xor(mx, 16));
    mx = fmaxf(mx, __shfl_xor(mx, 32));
    float sum = 0.f;
#pragma unroll
    for (int mi = 0; mi < 4; ++mi)
#pragma unroll
      for (int r = 0; r < 4; ++r) {
        v[mi][r] = __expf(v[mi][r] - mx);
        sum += v[mi][r];
      }
    sum += __shfl_xor(sum, 16);
    sum += __shfl_xor(sum, 32);
    const float rinv = __builtin_amdgcn_rcpf(sum);

    unsigned pk[4][2];
#pragma unroll
    for (int mi = 0; mi < 4; ++mi) {
      pk[mi][0] = pack2(v[mi][0] * rinv, v[mi][1] * rinv);
      pk[mi][1] = pack2(v[mi][2] * rinv, v[mi][3] * rinv);
    }
    bf16x8 pf[2];
#pragma unroll
    for (int ks = 0; ks < 2; ++ks) {
      unsigned a0 = (unsigned)__shfl((int)pk[2 * ks][0], src0);
      unsigned b0 = (unsigned)__shfl((int)pk[2 * ks + 1][0], src0);
      unsigned a1 = (unsigned)__shfl((int)pk[2 * ks][1], src0);
      unsigned b1 = (unsigned)__shfl((int)pk[2 * ks + 1][1], src0);
      unsigned a2 = (unsigned)__shfl((int)pk[2 * ks][0], src1);
      unsigned b2_ = (unsigned)__shfl((int)pk[2 * ks + 1][0], src1);
      unsigned a3 = (unsigned)__shfl((int)pk[2 * ks][1], src1);
      unsigned b3 = (unsigned)__shfl((int)pk[2 * ks + 1][1], src1);
      u32x4 ww = {hi5 ? b0 : a0, hi5 ? b1 : a1, hi5 ? b2_ : a2, hi5 ? b3 : a3};
      pf[ks] = __builtin_bit_cast(bf16x8, ww);
    }

    f32x4 o0 = __builtin_amdgcn_mfma_f32_16x16x32_bf16(vtf[0][0], pf[0], z4, 0, 0, 0);
    o0 = __builtin_amdgcn_mfma_f32_16x16x32_bf16(vtf[0][1], pf[1], o0, 0, 0, 0);
    f32x4 o1 = __builtin_amdgcn_mfma_f32_16x16x32_bf16(vtf[1][0], pf[0], z4, 0, 0, 0);
    o1 = __builtin_amdgcn_mfma_f32_16x16x32_bf16(vtf[1][1], pf[1], o1, 0, 0, 0);

    if (n < 49) {
      u16* dst = y + ((size_t)b * 49 + n) * 384 + h * 32 + lg * 4;
      u16x4 w0 = {f2b(o0[0]), f2b(o0[1]), f2b(o0[2]), f2b(o0[3])};
      u16x4 w1 = {f2b(o1[0]), f2b(o1[1]), f2b(o1[2]), f2b(o1[3])};
      *reinterpret_cast<u16x4*>(dst) = w0;
      *reinterpret_cast<u16x4*>(dst + 16) = w1;
    }
  }
}

// ---------------- launcher ----------------
extern "C" void kernel_launch(void* const* d_in, const int* in_sizes, int n_in,
                              void* d_out, int out_size, void* d_ws,
                              size_t ws_size, hipStream_t stream) {
  (void)in_sizes; (void)n_in; (void)out_size; (void)ws_size;
  const float* x      = (const float*)d_in[0];
  const float* mask   = (const float*)d_in[1];
  const float* qkv_w  = (const float*)d_in[2];
  const float* qkv_b  = (const float*)d_in[3];
  const float* tau    = (const float*)d_in[4];
  const float* cpb_w1 = (const float*)d_in[5];
  const float* cpb_b1 = (const float*)d_in[6];
  const float* cpb_w2 = (const float*)d_in[7];
  const float* cpb_b2 = (const float*)d_in[8];
  const float* proj_w = (const float*)d_in[9];
  const float* proj_b = (const float*)d_in[10];
  float* out = (float*)d_out;

  char* ws = (char*)d_ws;
  u16* x_bf     = (u16*)(ws);                 // 77,070,336 B (y_bf overlays)
  u16* y_bf     = (u16*)(ws);
  u16* qkvw_bf  = (u16*)(ws + 77070336);      // [1280][384]
  u16* projw_bf = (u16*)(ws + 78053376);
  float* cpb_t  = (float*)(ws + 78348288);
  float* qkvb_p = (float*)(ws + 78464000);    // f32[1280]
  u16* qkv_bf   = (u16*)(ws + 78469120);      // [100352][1280]
  float* comb   = (float*)(ws + 335370240);

  // pad-region init (deterministic every call)
  hipMemsetAsync(qkvw_bf + 1152 * 384, 0, (1280 - 1152) * 384 * 2, stream);
  hipMemsetAsync(qkvb_p, 0, 1280 * 4, stream);
  hipMemcpyAsync(qkvb_p, qkv_b, 1152 * 4, hipMemcpyDeviceToDevice, stream);

  k_cast<<<dim3(18816), dim3(256), 0, stream>>>(x, x_bf, 4816896);
  k_cast<<<dim3(216), dim3(256), 0, stream>>>(qkv_w, qkvw_bf, 55296);
  k_cast<<<dim3(72), dim3(256), 0, stream>>>(proj_w, projw_bf, 18432);
  k_cpb<<<dim3(38), dim3(64), 0, stream>>>(cpb_w1, cpb_b1, cpb_w2, cpb_b2, cpb_t);
  k_comb<<<dim3(768), dim3(256), 0, stream>>>(cpb_t, mask, comb);

  // qkv = x @ qkv_w^T + b  (M=100352, Npad=1280, K=384): 392 x 5 tiles
  k_gemmQ<<<dim3(392 * 5), dim3(512), 0, stream>>>(x_bf, qkvw_bf, qkvb_p, qkv_bf);

  k_attn<<<dim3(2048, 12), dim3(64), 0, stream>>>(qkv_bf, tau, comb, y_bf);

  // out = y @ proj_w^T + proj_b (M=100352, N=384, K=384): 784 x 3 tiles
  k_gemm_bt<true><<<dim3(784 * 3), dim3(256), 0, stream>>>(
      y_bf, projw_bf, proj_b, out, 100352, 384, 384);
}

// Round 6
// 425.313 us; speedup vs baseline: 1.0598x; 1.0434x over previous
//
#include <hip/hip_runtime.h>

// SwinV2 window attention, MI355X.
//   prep: cast weights+x -> bf16, CPB table, combined bias comb[h][w][n][52]
//   k_gemm<false>: qkv = x @ qkv_w^T + b   (bf16 MFMA, bf16 out)
//   k_attn: per (window,head); S^T = mfma(K,Q) -> in-register softmax
//   k_gemm<true>:  out = y @ proj_w^T + b  (f32 out)
// R6: fat-wave GEMM. 128x128 tile, 2 waves, per-wave 64x128 (acc 4x8):
//     12 ds_read_b128 -> 32 MFMA per K-step (2.67 MFMA/read vs R3's 2.0),
//     2x MFMA ILP/wave. Proven R3 2-phase dbuf sync + XOR swizzle (0 confl)
//     + XCD remap. N=1152 native again (padding dropped).
//
// Workspace layout (bytes):
//   0          x_bf      77,070,336
//   77070336   qkvw_bf      884,736
//   77955072   projw_bf     294,912
//   78249984   cpb_t        115,712
//   78365696   qkv_bf   231,211,008
//   309576704  y_bf      77,070,336
//   386647040  comb       7,827,456
//   total ~394.5 MB

typedef float f32x4 __attribute__((ext_vector_type(4)));
typedef __bf16 bf16x8 __attribute__((ext_vector_type(8)));
typedef unsigned short u16;
typedef u16 u16x8 __attribute__((ext_vector_type(8)));
typedef u16 u16x4 __attribute__((ext_vector_type(4)));
typedef unsigned u32x4 __attribute__((ext_vector_type(4)));

__device__ __forceinline__ float b2f(unsigned u) {
  return __builtin_bit_cast(float, u << 16);
}
__device__ __forceinline__ u16 f2b(float f) {  // RNE f32->bf16
  unsigned u = __builtin_bit_cast(unsigned, f);
  u += 0x7fffu + ((u >> 16) & 1u);
  return (u16)(u >> 16);
}
__device__ __forceinline__ unsigned pack2(float a, float b) {
  return (unsigned)f2b(a) | ((unsigned)f2b(b) << 16);
}

#define GLD16(gp, lp)                                        \
  __builtin_amdgcn_global_load_lds(                          \
      (const __attribute__((address_space(1))) void*)(gp),   \
      (__attribute__((address_space(3))) void*)(lp), 16, 0, 0)

// ---------------- cast f32 -> bf16, 8 elems/thread ----------------
__global__ __launch_bounds__(256) void k_cast(const float* __restrict__ in,
                                              u16* __restrict__ out, int n8) {
  int i = blockIdx.x * 256 + threadIdx.x;
  if (i >= n8) return;
  const float4* p = reinterpret_cast<const float4*>(in) + (size_t)i * 2;
  float4 a = p[0], b = p[1];
  u16x8 r;
  r[0] = f2b(a.x); r[1] = f2b(a.y); r[2] = f2b(a.z); r[3] = f2b(a.w);
  r[4] = f2b(b.x); r[5] = f2b(b.y); r[6] = f2b(b.z); r[7] = f2b(b.w);
  *(reinterpret_cast<u16x8*>(out) + i) = r;
}

// ---------------- CPB bias table: cpb_t[h][n][m] ----------------
__global__ __launch_bounds__(64) void k_cpb(const float* __restrict__ w1,
                                            const float* __restrict__ b1,
                                            const float* __restrict__ w2,
                                            const float* __restrict__ b2,
                                            float* __restrict__ cpb_t) {
  int p = blockIdx.x * 64 + threadIdx.x;
  if (p >= 49 * 49) return;
  int n = p / 49, m = p % 49;
  float d0 = (float)(n / 7 - m / 7);
  float d1 = (float)(n % 7 - m % 7);
  float a0 = log1pf(fabsf(d0)); a0 = (d0 < 0.f) ? -a0 : a0;
  float a1 = log1pf(fabsf(d1)); a1 = (d1 < 0.f) ? -a1 : a1;
  float acc[12];
#pragma unroll
  for (int h = 0; h < 12; ++h) acc[h] = b2[h];
  for (int j = 0; j < 64; ++j) {
    float hj = fmaxf(a0 * w1[2 * j] + a1 * w1[2 * j + 1] + b1[j], 0.f);
#pragma unroll
    for (int h = 0; h < 12; ++h) acc[h] += hj * w2[h * 64 + j];
  }
#pragma unroll
  for (int h = 0; h < 12; ++h) cpb_t[h * 2401 + p] = acc[h];
}

// ---------------- combined bias: comb[(h*64+w)*49+n][52] = cpb + mask --------
__global__ __launch_bounds__(256) void k_comb(const float* __restrict__ cpb_t,
                                              const float* __restrict__ mask,
                                              float* __restrict__ comb) {
  const int wh = blockIdx.x;  // h*64 + w
  const int h = wh >> 6, w = wh & 63;
  const float* c = cpb_t + h * 2401;
  const float* m = mask + (size_t)w * 2401;
  float* o = comb + (size_t)wh * 2548;
  for (int p = threadIdx.x; p < 2548; p += 256) {
    int n = p / 52, mc = p % 52;
    float v = (mc < 49) ? c[n * 49 + mc] + m[n * 49 + mc] : 0.f;
    o[p] = v;
  }
}

// ---------------- GEMM: C[M,N] = A[M,384] @ W[N,384]^T + bias ----------------
// 128x128 tile, BK=32, 128 thr (2 waves), per-wave 64x128 (acc 4x8):
// per K-step 12 ds_read_b128 -> 32 MFMA. Dbuf LDS 32KB -> 4 blocks/CU.
// gld_lds w16 staging; XOR swizzle both sides (slot ^= (row>>1)&3, 0-conflict
// measured R3); XCD-aware bijective bid remap (grids divisible by 8).
template <bool OUT_F32>
__global__ __launch_bounds__(128, 2) void k_gemm(
    const u16* __restrict__ A, const u16* __restrict__ W,
    const float* __restrict__ bias, void* __restrict__ Cv, int N) {
  __shared__ __align__(16) u16 sA[2][4096];  // [128][32]
  __shared__ __align__(16) u16 sB[2][4096];
  const int tid = threadIdx.x;
  const int cpx = (int)(gridDim.x >> 3);
  int bid = (int)blockIdx.x;
  bid = (bid & 7) * cpx + (bid >> 3);
  const int nt = N >> 7;
  const int m0 = (bid / nt) << 7;
  const int n0 = (bid % nt) << 7;

  // staging: issue i covers rows i*32..i*32+31; thread -> row r0, 16B slot
  const int r0 = tid >> 2;                                 // 0..31
  const int gc = (((tid & 3) ^ ((r0 >> 1) & 3)) << 3);     // swizzled col grp
  const u16* gA = A + (size_t)(m0 + r0) * 384 + gc;
  const u16* gB = W + (size_t)(n0 + r0) * 384 + gc;

#define STAGE(buf, kk)                                  \
  do {                                                  \
    GLD16(gA + (kk), &sA[buf][tid * 8]);                \
    GLD16(gA + 12288 + (kk), &sA[buf][1024 + tid * 8]); \
    GLD16(gA + 24576 + (kk), &sA[buf][2048 + tid * 8]); \
    GLD16(gA + 36864 + (kk), &sA[buf][3072 + tid * 8]); \
    GLD16(gB + (kk), &sB[buf][tid * 8]);                \
    GLD16(gB + 12288 + (kk), &sB[buf][1024 + tid * 8]); \
    GLD16(gB + 24576 + (kk), &sB[buf][2048 + tid * 8]); \
    GLD16(gB + 36864 + (kk), &sB[buf][3072 + tid * 8]); \
  } while (0)

  STAGE(0, 0);

  const int l = tid & 63, w = tid >> 6;
  const int lr = l & 15, lg = l >> 4;
  const int sl = ((lg ^ ((lr >> 1) & 3)) << 3);  // swizzled read col offset
  int aOff[4], bOff[8];
#pragma unroll
  for (int i = 0; i < 4; ++i) aOff[i] = ((w * 64 + i * 16 + lr) << 5) + sl;
#pragma unroll
  for (int j = 0; j < 8; ++j) bOff[j] = ((j * 16 + lr) << 5) + sl;

  const f32x4 z4 = {0.f, 0.f, 0.f, 0.f};
  f32x4 acc[4][8];
#pragma unroll
  for (int i = 0; i < 4; ++i)
#pragma unroll
    for (int j = 0; j < 8; ++j) acc[i][j] = z4;

#pragma unroll 4
  for (int t = 0; t < 12; ++t) {
    __syncthreads();  // drains vmcnt: tile t resident in sA/sB[t&1]
    if (t + 1 < 12) STAGE((t + 1) & 1, (t + 1) * 32);
    const u16* pa = sA[t & 1];
    const u16* pb = sB[t & 1];
    bf16x8 af[4], bq[8];
#pragma unroll
    for (int i = 0; i < 4; ++i)
      af[i] = __builtin_bit_cast(bf16x8,
          *reinterpret_cast<const u16x8*>(pa + aOff[i]));
#pragma unroll
    for (int j = 0; j < 8; ++j)
      bq[j] = __builtin_bit_cast(bf16x8,
          *reinterpret_cast<const u16x8*>(pb + bOff[j]));
#pragma unroll
    for (int i = 0; i < 4; ++i)
#pragma unroll
      for (int j = 0; j < 8; ++j)
        acc[i][j] = __builtin_amdgcn_mfma_f32_16x16x32_bf16(
            af[i], bq[j], acc[i][j], 0, 0, 0);
  }
#undef STAGE

  float bv[8];
#pragma unroll
  for (int j = 0; j < 8; ++j) bv[j] = bias[n0 + j * 16 + lr];
#pragma unroll
  for (int i = 0; i < 4; ++i)
#pragma unroll
    for (int rr = 0; rr < 4; ++rr) {
      const size_t row = (size_t)(m0 + w * 64 + i * 16 + lg * 4 + rr);
#pragma unroll
      for (int j = 0; j < 8; ++j) {
        const int col = n0 + j * 16 + lr;
        float v = acc[i][j][rr] + bv[j];
        if (OUT_F32)
          reinterpret_cast<float*>(Cv)[row * N + col] = v;
        else
          reinterpret_cast<u16*>(Cv)[row * N + col] = f2b(v);
      }
    }
}

// ---------------- attention: one wave per (window b, head h) ----------------
__global__ __launch_bounds__(64, 4) void k_attn(
    const u16* __restrict__ qkv, const float* __restrict__ tau,
    const float* __restrict__ comb, u16* __restrict__ y) {
  const int b = blockIdx.x, h = blockIdx.y;
  const int l = threadIdx.x;
  __shared__ __align__(16) u16 lk[64][40];  // 5120 B, overlaid by vt
  __shared__ __align__(16) u16 lq[64][40];  // 5120 B, live throughout
  u16(*vt)[72] = reinterpret_cast<u16(*)[72]>(&lk[0][0]);  // [32][72]

  const float tauh = fmaxf(tau[h], 0.01f);
  const bool valid = l < 49;
  u16x8 v8s[4];
  {
    const u16* base = qkv + ((size_t)b * 49 + (valid ? l : 0)) * 1152 + h * 32;
    float qv[32], kv[32];
#pragma unroll
    for (int c = 0; c < 4; ++c) {
      u16x8 q8 = {0, 0, 0, 0, 0, 0, 0, 0};
      u16x8 k8 = {0, 0, 0, 0, 0, 0, 0, 0};
      u16x8 v8 = {0, 0, 0, 0, 0, 0, 0, 0};
      if (valid) {
        q8 = *reinterpret_cast<const u16x8*>(base + c * 8);
        k8 = *reinterpret_cast<const u16x8*>(base + 384 + c * 8);
        v8 = *reinterpret_cast<const u16x8*>(base + 768 + c * 8);
      }
      v8s[c] = v8;
#pragma unroll
      for (int e = 0; e < 8; ++e) {
        qv[c * 8 + e] = b2f((unsigned)q8[e]);
        kv[c * 8 + e] = b2f((unsigned)k8[e]);
      }
    }
    float sq = 0.f, sk = 0.f;
#pragma unroll
    for (int j = 0; j < 32; ++j) { sq += qv[j] * qv[j]; sk += kv[j] * kv[j]; }
    const float qs = (1.f / fmaxf(sqrtf(sq), 1e-12f)) / tauh;  // fold 1/tau
    const float ks = 1.f / fmaxf(sqrtf(sk), 1e-12f);
#pragma unroll
    for (int c = 0; c < 4; ++c) {
      u16x8 wq, wk;
#pragma unroll
      for (int e = 0; e < 8; ++e) {
        wq[e] = f2b(qv[c * 8 + e] * qs);
        wk[e] = f2b(kv[c * 8 + e] * ks);
      }
      *reinterpret_cast<u16x8*>(&lq[l][c * 8]) = wq;
      *reinterpret_cast<u16x8*>(&lk[l][c * 8]) = wk;
    }
  }
  __syncthreads();

  const int lr = l & 15, lg = l >> 4;
  bf16x8 kf[4];
#pragma unroll
  for (int mi = 0; mi < 4; ++mi)
    kf[mi] = __builtin_bit_cast(bf16x8,
        *reinterpret_cast<const u16x8*>(&lk[mi * 16 + lr][lg * 8]));
  __syncthreads();  // lk dead -> overlay vt
#pragma unroll
  for (int c = 0; c < 4; ++c)
#pragma unroll
    for (int e = 0; e < 8; ++e) vt[c * 8 + e][l] = v8s[c][e];
  __syncthreads();
  bf16x8 vtf[2][2];
#pragma unroll
  for (int dd = 0; dd < 2; ++dd)
#pragma unroll
    for (int ks = 0; ks < 2; ++ks)
      vtf[dd][ks] = __builtin_bit_cast(bf16x8,
          *reinterpret_cast<const u16x8*>(&vt[dd * 16 + lr][ks * 32 + lg * 8]));

  const f32x4 z4 = {0.f, 0.f, 0.f, 0.f};
  const int src0 = lr + 16 * ((2 * lg) & 3);
  const int src1 = lr + 16 * ((2 * lg + 1) & 3);
  const bool hi5 = lg >= 2;
  const float* bbase = comb + (size_t)(h * 64 + (b & 63)) * 2548;

#pragma unroll
  for (int nj = 0; nj < 4; ++nj) {
    const bf16x8 qf = __builtin_bit_cast(bf16x8,
        *reinterpret_cast<const u16x8*>(&lq[nj * 16 + lr][lg * 8]));
    f32x4 s[4];
#pragma unroll
    for (int mi = 0; mi < 4; ++mi)
      s[mi] = __builtin_amdgcn_mfma_f32_16x16x32_bf16(kf[mi], qf, z4, 0, 0, 0);

    const int n = nj * 16 + lr;
    const float* bp = bbase + (size_t)(n < 49 ? n : 48) * 52 + lg * 4;
    f32x4 bia[4];
#pragma unroll
    for (int mi = 0; mi < 4; ++mi)
      bia[mi] = *reinterpret_cast<const f32x4*>(bp + mi * 16);

    float v[4][4];
#pragma unroll
    for (int mi = 0; mi < 3; ++mi)  // m <= 47: all valid
#pragma unroll
      for (int r = 0; r < 4; ++r) v[mi][r] = s[mi][r] + bia[mi][r];
#pragma unroll
    for (int r = 0; r < 4; ++r) {  // mi=3: only m=48 (lg==0, r==0) valid
      float t = s[3][r] + bia[3][r];
      v[3][r] = (lg == 0 && r == 0) ? t : -1e30f;
    }

    float mx = v[0][0];
#pragma unroll
    for (int mi = 0; mi < 4; ++mi)
#pragma unroll
      for (int r = 0; r < 4; ++r) mx = fmaxf(mx, v[mi][r]);
    mx = fmaxf(mx, __shfl_xor(mx, 16));
    mx = fmaxf(mx, __shfl_xor(mx, 32));
    float sum = 0.f;
#pragma unroll
    for (int mi = 0; mi < 4; ++mi)
#pragma unroll
      for (int r = 0; r < 4; ++r) {
        v[mi][r] = __expf(v[mi][r] - mx);
        sum += v[mi][r];
      }
    sum += __shfl_xor(sum, 16);
    sum += __shfl_xor(sum, 32);
    const float rinv = __builtin_amdgcn_rcpf(sum);

    unsigned pk[4][2];
#pragma unroll
    for (int mi = 0; mi < 4; ++mi) {
      pk[mi][0] = pack2(v[mi][0] * rinv, v[mi][1] * rinv);
      pk[mi][1] = pack2(v[mi][2] * rinv, v[mi][3] * rinv);
    }
    bf16x8 pf[2];
#pragma unroll
    for (int ks = 0; ks < 2; ++ks) {
      unsigned a0 = (unsigned)__shfl((int)pk[2 * ks][0], src0);
      unsigned b0 = (unsigned)__shfl((int)pk[2 * ks + 1][0], src0);
      unsigned a1 = (unsigned)__shfl((int)pk[2 * ks][1], src0);
      unsigned b1 = (unsigned)__shfl((int)pk[2 * ks + 1][1], src0);
      unsigned a2 = (unsigned)__shfl((int)pk[2 * ks][0], src1);
      unsigned b2_ = (unsigned)__shfl((int)pk[2 * ks + 1][0], src1);
      unsigned a3 = (unsigned)__shfl((int)pk[2 * ks][1], src1);
      unsigned b3 = (unsigned)__shfl((int)pk[2 * ks + 1][1], src1);
      u32x4 ww = {hi5 ? b0 : a0, hi5 ? b1 : a1, hi5 ? b2_ : a2, hi5 ? b3 : a3};
      pf[ks] = __builtin_bit_cast(bf16x8, ww);
    }

    f32x4 o0 = __builtin_amdgcn_mfma_f32_16x16x32_bf16(vtf[0][0], pf[0], z4, 0, 0, 0);
    o0 = __builtin_amdgcn_mfma_f32_16x16x32_bf16(vtf[0][1], pf[1], o0, 0, 0, 0);
    f32x4 o1 = __builtin_amdgcn_mfma_f32_16x16x32_bf16(vtf[1][0], pf[0], z4, 0, 0, 0);
    o1 = __builtin_amdgcn_mfma_f32_16x16x32_bf16(vtf[1][1], pf[1], o1, 0, 0, 0);

    if (n < 49) {
      u16* dst = y + ((size_t)b * 49 + n) * 384 + h * 32 + lg * 4;
      u16x4 w0 = {f2b(o0[0]), f2b(o0[1]), f2b(o0[2]), f2b(o0[3])};
      u16x4 w1 = {f2b(o1[0]), f2b(o1[1]), f2b(o1[2]), f2b(o1[3])};
      *reinterpret_cast<u16x4*>(dst) = w0;
      *reinterpret_cast<u16x4*>(dst + 16) = w1;
    }
  }
}

// ---------------- launcher ----------------
extern "C" void kernel_launch(void* const* d_in, const int* in_sizes, int n_in,
                              void* d_out, int out_size, void* d_ws,
                              size_t ws_size, hipStream_t stream) {
  (void)in_sizes; (void)n_in; (void)out_size; (void)ws_size;
  const float* x      = (const float*)d_in[0];
  const float* mask   = (const float*)d_in[1];
  const float* qkv_w  = (const float*)d_in[2];
  const float* qkv_b  = (const float*)d_in[3];
  const float* tau    = (const float*)d_in[4];
  const float* cpb_w1 = (const float*)d_in[5];
  const float* cpb_b1 = (const float*)d_in[6];
  const float* cpb_w2 = (const float*)d_in[7];
  const float* cpb_b2 = (const float*)d_in[8];
  const float* proj_w = (const float*)d_in[9];
  const float* proj_b = (const float*)d_in[10];
  float* out = (float*)d_out;

  char* ws = (char*)d_ws;
  u16* x_bf     = (u16*)(ws);
  u16* qkvw_bf  = (u16*)(ws + 77070336);
  u16* projw_bf = (u16*)(ws + 77955072);
  float* cpb_t  = (float*)(ws + 78249984);
  u16* qkv_bf   = (u16*)(ws + 78365696);
  u16* y_bf     = (u16*)(ws + 309576704);
  float* comb   = (float*)(ws + 386647040);

  k_cast<<<dim3(18816), dim3(256), 0, stream>>>(x, x_bf, 4816896);
  k_cast<<<dim3(216), dim3(256), 0, stream>>>(qkv_w, qkvw_bf, 55296);
  k_cast<<<dim3(72), dim3(256), 0, stream>>>(proj_w, projw_bf, 18432);
  k_cpb<<<dim3(38), dim3(64), 0, stream>>>(cpb_w1, cpb_b1, cpb_w2, cpb_b2, cpb_t);
  k_comb<<<dim3(768), dim3(256), 0, stream>>>(cpb_t, mask, comb);

  // qkv = x @ qkv_w^T + qkv_b   (M=100352, N=1152, K=384): 784 x 9 tiles
  k_gemm<false><<<dim3(784 * 9), dim3(128), 0, stream>>>(
      x_bf, qkvw_bf, qkv_b, qkv_bf, 1152);

  k_attn<<<dim3(2048, 12), dim3(64), 0, stream>>>(qkv_bf, tau, comb, y_bf);

  // out = y @ proj_w^T + proj_b (M=100352, N=384, K=384): 784 x 3 tiles
  k_gemm<true><<<dim3(784 * 3), dim3(128), 0, stream>>>(
      y_bf, projw_bf, proj_b, out, 384);
}